// Round 28
// baseline (39.812 us; speedup 1.0000x reference)
//
#include <hip/hip_runtime.h>
#include <math.h>

constexpr int IN_C = 31;
constexpr int TOT  = 44;
constexpr int HW   = 256 * 256;
constexpr int NPIX = 4 * HW;
constexpr int NWG  = NPIX / 64;      // 4096 workgroups
constexpr float SMIN = 0.001f, SMAX = 1000.0f;

typedef __attribute__((ext_vector_type(8))) short bf16x8;
typedef __attribute__((ext_vector_type(4))) float f32x4;

__device__ __forceinline__ float frcp(float v) { return __builtin_amdgcn_rcpf(v); }

__device__ __forceinline__ short f2bf(float f) {
    union { float f; unsigned u; } v; v.f = f;
    unsigned r = v.u + 0x7FFFu + ((v.u >> 16) & 1u);   // RNE
    return (short)(r >> 16);
}
__device__ __forceinline__ float bf2f(short h) {
    union { unsigned u; float f; } v; v.u = ((unsigned)(unsigned short)h) << 16;
    return v.f;
}

// ============ Kernel 1: encoder GEMV (MFMA) + m + intermediate ============
// Writes m (as R24) and a 36-float/pixel intermediate to ws in [chan][pixel]
// layout (coalesced): c'=0..7 -> sq (post sigmoid+sqrt), c'=8..35 -> rev
// angles (0.5*tanh). fp32 store round-trip is exact -> numerics identical.
// Low liveness (~70 VGPR) -> high natural occupancy.
__global__ __launch_bounds__(64, 4) void sepgpd_enc(
    const float* __restrict__ x,
    const float* __restrict__ Wenc,
    const float* __restrict__ benc,
    float* __restrict__ out,
    float* __restrict__ ws)
{
    __shared__ float wt[64 * 34];   // transpose buffer

    const int lane = threadIdx.x;
    const int W0   = blockIdx.x * 64;
    const int b    = W0 >> 16;
    const int hwb  = W0 & (HW - 1);
    const int lrow = lane & 15;
    const int lgrp = lane >> 4;

    const float* xb = x + (size_t)b * IN_C * HW + hwb;

    // ---- B fragments ----
    bf16x8 bhi[3], blo[3];
#pragma unroll
    for (int n = 0; n < 3; ++n) {
        const int o = n * 16 + lrow;
#pragma unroll
        for (int j = 0; j < 8; ++j) {
            const int k = lgrp * 8 + j;
            const float wv = (o < TOT && k < IN_C) ? Wenc[o * IN_C + k] : 0.0f;
            const short h = f2bf(wv);
            bhi[n][j] = h;
            blo[n][j] = f2bf(wv - bf2f(h));
        }
    }

    // ---- MFMA ----
    f32x4 acc[4][3];
#pragma unroll
    for (int t = 0; t < 4; ++t)
#pragma unroll
        for (int n = 0; n < 3; ++n) acc[t][n] = (f32x4)0.0f;

#pragma unroll
    for (int t = 0; t < 4; ++t) {
        float xf[8];
#pragma unroll
        for (int j = 0; j < 8; ++j) {
            const int k = lgrp * 8 + j;
            xf[j] = (k < IN_C) ? xb[(size_t)k * HW + t * 16 + lrow] : 0.0f;
        }
        bf16x8 ahi, alo;
#pragma unroll
        for (int j = 0; j < 8; ++j) {
            const short h = f2bf(xf[j]);
            ahi[j] = h;
            alo[j] = f2bf(xf[j] - bf2f(h));
        }
#pragma unroll
        for (int n = 0; n < 3; ++n) {
            acc[t][n] = __builtin_amdgcn_mfma_f32_16x16x32_bf16(ahi, bhi[n], acc[t][n], 0, 0, 0);
            acc[t][n] = __builtin_amdgcn_mfma_f32_16x16x32_bf16(alo, bhi[n], acc[t][n], 0, 0, 0);
            acc[t][n] = __builtin_amdgcn_mfma_f32_16x16x32_bf16(ahi, blo[n], acc[t][n], 0, 0, 0);
        }
    }

    // ---- transpose phase A: chans 0..31 ----
#pragma unroll
    for (int t = 0; t < 4; ++t)
#pragma unroll
        for (int n = 0; n < 2; ++n)
#pragma unroll
            for (int r = 0; r < 4; ++r) {
                const int p = t * 16 + lgrp * 4 + r;
                wt[p * 34 + n * 16 + lrow] = acc[t][n][r];
            }

    float a16[16];
#pragma unroll
    for (int c = 0; c < 16; ++c) a16[c] = wt[lane * 34 + c];

    asm volatile("" ::: "memory");

    // phase B: chans 32..43 -> cols 0..15
#pragma unroll
    for (int t = 0; t < 4; ++t)
#pragma unroll
        for (int r = 0; r < 4; ++r) {
            const int p = t * 16 + lgrp * 4 + r;
            wt[p * 34 + lrow] = acc[t][2][r];
        }

    // ---- m ----
    const int pix = W0 + lane;
    float4* mp = reinterpret_cast<float4*>(out + (size_t)pix * 8);
    mp[0] = make_float4(a16[0] + benc[0], a16[1] + benc[1],
                        a16[2] + benc[2], a16[3] + benc[3]);
    mp[1] = make_float4(a16[4] + benc[4], a16[5] + benc[5],
                        a16[6] + benc[6], a16[7] + benc[7]);

    // ---- sq -> ws[0..7] (coalesced per chan) ----
#pragma unroll
    for (int j = 0; j < 8; ++j) {
        const float sig = frcp(1.0f + __expf(-(a16[8 + j] + benc[8 + j])));
        const float s   = fmaf(SMAX - SMIN, sig, SMIN);
        ws[(size_t)j * NPIX + pix] = __builtin_amdgcn_sqrtf(s);
    }

    // ---- rev angles -> ws[8..35] (same col mapping + math as R24) ----
#pragma unroll
    for (int cc = 0; cc < 28; ++cc) {
        const int  col = (cc < 16) ? (16 + cc) : (cc - 16);
        const float wv = wt[lane * 34 + col] + benc[16 + cc];
        const float th = fmaf(-2.0f, frcp(__expf(2.0f * wv) + 1.0f), 1.0f);
        ws[(size_t)(8 + cc) * NPIX + pix] = 0.5f * th;
    }
}

// ============ Kernel 2: R chain + S = R^T D R + coalesced flush ============
__global__ __launch_bounds__(64, 4) void sepgpd_tail(
    const float* __restrict__ ws,
    float* __restrict__ out)
{
    __shared__ float4 wbuf4[512];   // 8 KB staging

    const int lane = threadIdx.x;
    const int W0   = blockIdx.x * 64;
    const int pix  = W0 + lane;

    // ---- all 36 inputs issued upfront (coalesced, in flight together) ----
    float sq[8];
#pragma unroll
    for (int j = 0; j < 8; ++j) sq[j] = ws[(size_t)j * NPIX + pix];
    float rev[28];
#pragma unroll
    for (int cc = 0; cc < 28; ++cc) rev[cc] = ws[(size_t)(8 + cc) * NPIX + pix];

    // ---- R from Givens chain (hw sin/cos in revolutions) ----
    float R[8][8];
#pragma unroll
    for (int i = 0; i < 8; ++i)
#pragma unroll
        for (int k = 0; k < 8; ++k) R[i][k] = (i == k) ? 1.0f : 0.0f;

    int cc = 0;
#pragma unroll
    for (int i = 0; i < 7; ++i) {
#pragma unroll
        for (int j = i + 1; j < 8; ++j) {
            const float cs = __builtin_amdgcn_cosf(rev[cc]);
            const float ss = __builtin_amdgcn_sinf(rev[cc]);
#pragma unroll
            for (int r = 0; r < 8; ++r) {
                const float ri = R[r][i];
                const float rj = R[r][j];
                R[r][i] = fmaf(ri, cs, rj * ss);
                R[r][j] = fmaf(rj, cs, -(ri * ss));
            }
            ++cc;
        }
    }

    // scale row j by sq[j]
#pragma unroll
    for (int j = 0; j < 8; ++j)
#pragma unroll
        for (int k = 0; k < 8; ++k) R[j][k] *= sq[j];

    // ---- S rows one at a time -> staging -> coalesced flush ----
    float4* S4 = reinterpret_cast<float4*>(out + (size_t)NPIX * 8);
    const size_t pixbase4 = (size_t)W0 * 16;

#pragma unroll
    for (int p = 0; p < 2; ++p) {
#pragma unroll
        for (int r = 0; r < 4; ++r) {
            const int i = 4 * p + r;
            float row[8];
#pragma unroll
            for (int k = 0; k < 8; ++k) {
                float d = 0.0f;
#pragma unroll
                for (int j = 0; j < 8; ++j) d = fmaf(R[j][i], R[j][k], d);
                row[k] = d;
            }
            const int v0 = r * 2, v1 = v0 + 1;
            wbuf4[lane * 8 + (v0 ^ (lane & 7))] =
                make_float4(row[0], row[1], row[2], row[3]);
            wbuf4[lane * 8 + (v1 ^ (lane & 7))] =
                make_float4(row[4], row[5], row[6], row[7]);
        }
#pragma unroll
        for (int k = 0; k < 8; ++k) {
            const int t  = k * 64 + lane;
            const int pl = t >> 3;
            const int v  = t & 7;
            S4[pixbase4 + (size_t)pl * 16 + p * 8 + v] =
                wbuf4[pl * 8 + (v ^ (pl & 7))];
        }
    }
}

// ============ Fallback: exact R24 single kernel (proven 27.2us) ============
__global__ __launch_bounds__(64, 4) void sepgpd_fused(
    const float* __restrict__ x,
    const float* __restrict__ Wenc,
    const float* __restrict__ benc,
    float* __restrict__ out)
{
    __shared__ float wt[64 * 34];

    const int lane = threadIdx.x;
    const int W0   = blockIdx.x * 64;
    const int b    = W0 >> 16;
    const int hwb  = W0 & (HW - 1);
    const int lrow = lane & 15;
    const int lgrp = lane >> 4;

    const float* xb = x + (size_t)b * IN_C * HW + hwb;

    bf16x8 bhi[3], blo[3];
#pragma unroll
    for (int n = 0; n < 3; ++n) {
        const int o = n * 16 + lrow;
#pragma unroll
        for (int j = 0; j < 8; ++j) {
            const int k = lgrp * 8 + j;
            const float wv = (o < TOT && k < IN_C) ? Wenc[o * IN_C + k] : 0.0f;
            const short h = f2bf(wv);
            bhi[n][j] = h;
            blo[n][j] = f2bf(wv - bf2f(h));
        }
    }

    f32x4 acc[4][3];
#pragma unroll
    for (int t = 0; t < 4; ++t)
#pragma unroll
        for (int n = 0; n < 3; ++n) acc[t][n] = (f32x4)0.0f;

#pragma unroll
    for (int t = 0; t < 4; ++t) {
        float xf[8];
#pragma unroll
        for (int j = 0; j < 8; ++j) {
            const int k = lgrp * 8 + j;
            xf[j] = (k < IN_C) ? xb[(size_t)k * HW + t * 16 + lrow] : 0.0f;
        }
        bf16x8 ahi, alo;
#pragma unroll
        for (int j = 0; j < 8; ++j) {
            const short h = f2bf(xf[j]);
            ahi[j] = h;
            alo[j] = f2bf(xf[j] - bf2f(h));
        }
#pragma unroll
        for (int n = 0; n < 3; ++n) {
            acc[t][n] = __builtin_amdgcn_mfma_f32_16x16x32_bf16(ahi, bhi[n], acc[t][n], 0, 0, 0);
            acc[t][n] = __builtin_amdgcn_mfma_f32_16x16x32_bf16(alo, bhi[n], acc[t][n], 0, 0, 0);
            acc[t][n] = __builtin_amdgcn_mfma_f32_16x16x32_bf16(ahi, blo[n], acc[t][n], 0, 0, 0);
        }
    }

#pragma unroll
    for (int t = 0; t < 4; ++t)
#pragma unroll
        for (int n = 0; n < 2; ++n)
#pragma unroll
            for (int r = 0; r < 4; ++r) {
                const int p = t * 16 + lgrp * 4 + r;
                wt[p * 34 + n * 16 + lrow] = acc[t][n][r];
            }

    float a16[16];
#pragma unroll
    for (int c = 0; c < 16; ++c) a16[c] = wt[lane * 34 + c];

    asm volatile("" ::: "memory");

#pragma unroll
    for (int t = 0; t < 4; ++t)
#pragma unroll
        for (int r = 0; r < 4; ++r) {
            const int p = t * 16 + lgrp * 4 + r;
            wt[p * 34 + lrow] = acc[t][2][r];
        }

    const int pix = W0 + lane;
    float4* mp = reinterpret_cast<float4*>(out + (size_t)pix * 8);
    mp[0] = make_float4(a16[0] + benc[0], a16[1] + benc[1],
                        a16[2] + benc[2], a16[3] + benc[3]);
    mp[1] = make_float4(a16[4] + benc[4], a16[5] + benc[5],
                        a16[6] + benc[6], a16[7] + benc[7]);

    float sq[8];
#pragma unroll
    for (int j = 0; j < 8; ++j) {
        const float sig = frcp(1.0f + __expf(-(a16[8 + j] + benc[8 + j])));
        const float s   = fmaf(SMAX - SMIN, sig, SMIN);
        sq[j] = __builtin_amdgcn_sqrtf(s);
    }

    float R[8][8];
#pragma unroll
    for (int i = 0; i < 8; ++i)
#pragma unroll
        for (int k = 0; k < 8; ++k) R[i][k] = (i == k) ? 1.0f : 0.0f;

    int cc = 0;
#pragma unroll
    for (int i = 0; i < 7; ++i) {
#pragma unroll
        for (int j = i + 1; j < 8; ++j) {
            const int  col = (cc < 16) ? (16 + cc) : (cc - 16);
            const float wv = wt[lane * 34 + col] + benc[16 + cc];
            const float th  = fmaf(-2.0f, frcp(__expf(2.0f * wv) + 1.0f), 1.0f);
            const float rev = 0.5f * th;
            const float cs  = __builtin_amdgcn_cosf(rev);
            const float ss  = __builtin_amdgcn_sinf(rev);
#pragma unroll
            for (int r = 0; r < 8; ++r) {
                const float ri = R[r][i];
                const float rj = R[r][j];
                R[r][i] = fmaf(ri, cs, rj * ss);
                R[r][j] = fmaf(rj, cs, -(ri * ss));
            }
            ++cc;
        }
    }

    asm volatile("" ::: "memory");

#pragma unroll
    for (int j = 0; j < 8; ++j)
#pragma unroll
        for (int k = 0; k < 8; ++k) R[j][k] *= sq[j];

    float4* wbuf4 = reinterpret_cast<float4*>(wt);
    float4* S4 = reinterpret_cast<float4*>(out + (size_t)NPIX * 8);
    const size_t pixbase4 = (size_t)W0 * 16;

#pragma unroll
    for (int p = 0; p < 2; ++p) {
#pragma unroll
        for (int r = 0; r < 4; ++r) {
            const int i = 4 * p + r;
            float row[8];
#pragma unroll
            for (int k = 0; k < 8; ++k) {
                float d = 0.0f;
#pragma unroll
                for (int j = 0; j < 8; ++j) d = fmaf(R[j][i], R[j][k], d);
                row[k] = d;
            }
            const int v0 = r * 2, v1 = v0 + 1;
            wbuf4[lane * 8 + (v0 ^ (lane & 7))] =
                make_float4(row[0], row[1], row[2], row[3]);
            wbuf4[lane * 8 + (v1 ^ (lane & 7))] =
                make_float4(row[4], row[5], row[6], row[7]);
        }
#pragma unroll
        for (int k = 0; k < 8; ++k) {
            const int t  = k * 64 + lane;
            const int pl = t >> 3;
            const int v  = t & 7;
            S4[pixbase4 + (size_t)pl * 16 + p * 8 + v] =
                wbuf4[pl * 8 + (v ^ (pl & 7))];
        }
    }
}

extern "C" void kernel_launch(void* const* d_in, const int* in_sizes, int n_in,
                              void* d_out, int out_size, void* d_ws, size_t ws_size,
                              hipStream_t stream)
{
    const float* x    = (const float*)d_in[0];
    const float* Wenc = (const float*)d_in[1];
    const float* benc = (const float*)d_in[2];
    float* out        = (float*)d_out;

    const size_t need = (size_t)NPIX * 36 * sizeof(float);   // 37.7 MB
    if (ws_size >= need) {
        float* ws = (float*)d_ws;
        sepgpd_enc <<<dim3(NWG), dim3(64), 0, stream>>>(x, Wenc, benc, out, ws);
        sepgpd_tail<<<dim3(NWG), dim3(64), 0, stream>>>(ws, out);
    } else {
        sepgpd_fused<<<dim3(NWG), dim3(64), 0, stream>>>(x, Wenc, benc, out);
    }
}

// Round 29
// 27.450 us; speedup vs baseline: 1.4504x; 1.4504x over previous
//
#include <hip/hip_runtime.h>
#include <math.h>

constexpr int IN_C = 31;
constexpr int TOT  = 44;
constexpr int HW   = 256 * 256;
constexpr int NPIX = 4 * HW;
constexpr int NWG  = NPIX / 64;      // 4096 workgroups
constexpr float SMIN = 0.001f, SMAX = 1000.0f;

typedef __attribute__((ext_vector_type(8))) short bf16x8;
typedef __attribute__((ext_vector_type(4))) float f32x4;

__device__ __forceinline__ float frcp(float v) { return __builtin_amdgcn_rcpf(v); }

__device__ __forceinline__ short f2bf(float f) {
    union { float f; unsigned u; } v; v.f = f;
    unsigned r = v.u + 0x7FFFu + ((v.u >> 16) & 1u);   // RNE
    return (short)(r >> 16);
}
__device__ __forceinline__ float bf2f(short h) {
    union { unsigned u; float f; } v; v.u = ((unsigned)(unsigned short)h) << 16;
    return v.f;
}

// FINAL: exact R24 (session best, proven 27.24us, absmax 4.0).
// Structure: 1-wave blocks (de-lockstepped scheduling, R19's -21% win),
// MFMA-based encoder GEMV (hi/lo bf16 split for ~fp32 accuracy, R11's -16%),
// two-phase LDS transpose, slim tail (a16 regs + angles-on-demand from LDS +
// row-at-a-time S), hw sin/cos in revolutions, two-phase coalesced S flush.
// Condemned by experiment: global_load_lds staging (R14-16), forced
// __launch_bounds__(64,5) (R21-23), 2 px/thread (R8/R10), n-pass GEMV (R25),
// kernel split (R28), XCD swizzle neutral (R27).
__global__ __launch_bounds__(64, 4) void sepgpd_fused(
    const float* __restrict__ x,
    const float* __restrict__ Wenc,
    const float* __restrict__ benc,
    float* __restrict__ out)
{
    __shared__ float wt[64 * 34];   // 8704 B: transpose + S staging

    const int lane = threadIdx.x;                   // 0..63
    const int W0   = blockIdx.x * 64;               // wave's first pixel
    const int b    = W0 >> 16;                      // 64 | 65536: same image
    const int hwb  = W0 & (HW - 1);
    const int lrow = lane & 15;                     // M/N lane index
    const int lgrp = lane >> 4;                     // K group

    const float* xb = x + (size_t)b * IN_C * HW + hwb;

    // ---- B fragments: W^T tiles (48 chans x 32 K), hi/lo bf16 split ----
    bf16x8 bhi[3], blo[3];
#pragma unroll
    for (int n = 0; n < 3; ++n) {
        const int o = n * 16 + lrow;
#pragma unroll
        for (int j = 0; j < 8; ++j) {
            const int k = lgrp * 8 + j;
            const float wv = (o < TOT && k < IN_C) ? Wenc[o * IN_C + k] : 0.0f;
            const short h = f2bf(wv);
            bhi[n][j] = h;
            blo[n][j] = f2bf(wv - bf2f(h));
        }
    }

    // ---- MFMA: 4 M-tiles x 3 N-tiles x 3 products (x loads per tile) ----
    f32x4 acc[4][3];
#pragma unroll
    for (int t = 0; t < 4; ++t)
#pragma unroll
        for (int n = 0; n < 3; ++n) acc[t][n] = (f32x4)0.0f;

#pragma unroll
    for (int t = 0; t < 4; ++t) {
        float xf[8];
#pragma unroll
        for (int j = 0; j < 8; ++j) {
            const int k = lgrp * 8 + j;
            xf[j] = (k < IN_C) ? xb[(size_t)k * HW + t * 16 + lrow] : 0.0f;
        }
        bf16x8 ahi, alo;
#pragma unroll
        for (int j = 0; j < 8; ++j) {
            const short h = f2bf(xf[j]);
            ahi[j] = h;
            alo[j] = f2bf(xf[j] - bf2f(h));
        }
#pragma unroll
        for (int n = 0; n < 3; ++n) {
            acc[t][n] = __builtin_amdgcn_mfma_f32_16x16x32_bf16(ahi, bhi[n], acc[t][n], 0, 0, 0);
            acc[t][n] = __builtin_amdgcn_mfma_f32_16x16x32_bf16(alo, bhi[n], acc[t][n], 0, 0, 0);
            acc[t][n] = __builtin_amdgcn_mfma_f32_16x16x32_bf16(ahi, blo[n], acc[t][n], 0, 0, 0);
        }
    }

    // ---- transpose phase A: chans 0..31 -> [p][c] stride 34 ----
#pragma unroll
    for (int t = 0; t < 4; ++t)
#pragma unroll
        for (int n = 0; n < 2; ++n)
#pragma unroll
            for (int r = 0; r < 4; ++r) {
                const int p = t * 16 + lgrp * 4 + r;      // pixel (C row)
                wt[p * 34 + n * 16 + lrow] = acc[t][n][r];
            }

    // read chans 0..15 (m + scales) as PLAIN float loads (alias-ordered)
    float a16[16];
#pragma unroll
    for (int c = 0; c < 16; ++c) a16[c] = wt[lane * 34 + c];

    asm volatile("" ::: "memory");   // fence: reads above before phase-B writes

    // phase B: chans 32..43 -> cols 0..15 (cols 16..31 keep angle chans 16..31)
#pragma unroll
    for (int t = 0; t < 4; ++t)
#pragma unroll
        for (int r = 0; r < 4; ++r) {
            const int p = t * 16 + lgrp * 4 + r;
            wt[p * 34 + lrow] = acc[t][2][r];
        }

    // ---- m: first 8 channels (+bias), per-pixel contiguous ----
    const int pix = W0 + lane;
    float4* mp = reinterpret_cast<float4*>(out + (size_t)pix * 8);
    mp[0] = make_float4(a16[0] + benc[0], a16[1] + benc[1],
                        a16[2] + benc[2], a16[3] + benc[3]);
    mp[1] = make_float4(a16[4] + benc[4], a16[5] + benc[5],
                        a16[6] + benc[6], a16[7] + benc[7]);

    // ---- sqrt scales (rcp-based sigmoid) ----
    float sq[8];
#pragma unroll
    for (int j = 0; j < 8; ++j) {
        const float sig = frcp(1.0f + __expf(-(a16[8 + j] + benc[8 + j])));
        const float s   = fmaf(SMAX - SMIN, sig, SMIN);
        sq[j] = __builtin_amdgcn_sqrtf(s);
    }

    // ---- R from Givens chain; angles on demand from LDS (plain float);
    //      hw sin/cos in revolutions: cos(pi*th) = v_cos(th/2) ----
    float R[8][8];
#pragma unroll
    for (int i = 0; i < 8; ++i)
#pragma unroll
        for (int k = 0; k < 8; ++k) R[i][k] = (i == k) ? 1.0f : 0.0f;

    int cc = 0;
#pragma unroll
    for (int i = 0; i < 7; ++i) {
#pragma unroll
        for (int j = i + 1; j < 8; ++j) {
            const int  col = (cc < 16) ? (16 + cc) : (cc - 16);
            const float wv = wt[lane * 34 + col] + benc[16 + cc];
            // tanh(wv) = 1 - 2/(e^{2wv}+1); saturates correctly for large |wv|
            const float th  = fmaf(-2.0f, frcp(__expf(2.0f * wv) + 1.0f), 1.0f);
            const float rev = 0.5f * th;
            const float cs  = __builtin_amdgcn_cosf(rev);
            const float ss  = __builtin_amdgcn_sinf(rev);
#pragma unroll
            for (int r = 0; r < 8; ++r) {
                const float ri = R[r][i];
                const float rj = R[r][j];
                R[r][i] = fmaf(ri, cs, rj * ss);
                R[r][j] = fmaf(rj, cs, -(ri * ss));
            }
            ++cc;
        }
    }

    asm volatile("" ::: "memory");   // fence: angle reads done before staging

    // scale row j by sqrt(s_j):  S = (sqrtD R)^T (sqrtD R)
#pragma unroll
    for (int j = 0; j < 8; ++j)
#pragma unroll
        for (int k = 0; k < 8; ++k) R[j][k] *= sq[j];

    // ---- S rows one at a time -> staging -> coalesced flush per 4 rows ----
    float4* wbuf4 = reinterpret_cast<float4*>(wt);
    float4* S4 = reinterpret_cast<float4*>(out + (size_t)NPIX * 8);
    const size_t pixbase4 = (size_t)W0 * 16;   // float4 units

#pragma unroll
    for (int p = 0; p < 2; ++p) {
#pragma unroll
        for (int r = 0; r < 4; ++r) {
            const int i = 4 * p + r;
            float row[8];
#pragma unroll
            for (int k = 0; k < 8; ++k) {
                float d = 0.0f;
#pragma unroll
                for (int j = 0; j < 8; ++j) d = fmaf(R[j][i], R[j][k], d);
                row[k] = d;
            }
            const int v0 = r * 2, v1 = v0 + 1;
            wbuf4[lane * 8 + (v0 ^ (lane & 7))] =
                make_float4(row[0], row[1], row[2], row[3]);
            wbuf4[lane * 8 + (v1 ^ (lane & 7))] =
                make_float4(row[4], row[5], row[6], row[7]);
        }
        // coalesced flush: 8 iters x 64 lanes x 16B = 8KB contiguous
#pragma unroll
        for (int k = 0; k < 8; ++k) {
            const int t  = k * 64 + lane;
            const int pl = t >> 3;           // local pixel 0..63
            const int v  = t & 7;            // float4 index within half
            S4[pixbase4 + (size_t)pl * 16 + p * 8 + v] =
                wbuf4[pl * 8 + (v ^ (pl & 7))];
        }
    }
}

extern "C" void kernel_launch(void* const* d_in, const int* in_sizes, int n_in,
                              void* d_out, int out_size, void* d_ws, size_t ws_size,
                              hipStream_t stream)
{
    const float* x    = (const float*)d_in[0];
    const float* Wenc = (const float*)d_in[1];
    const float* benc = (const float*)d_in[2];
    float* out        = (float*)d_out;

    dim3 grid(NWG), block(64);
    sepgpd_fused<<<grid, block, 0, stream>>>(x, Wenc, benc, out);
}